// Round 8
// baseline (668.940 us; speedup 1.0000x reference)
//
#include <hip/hip_runtime.h>
#include <hip/hip_bf16.h>

typedef __attribute__((ext_vector_type(8))) short bf16x8;
typedef __attribute__((ext_vector_type(4))) float f32x4;
typedef __attribute__((ext_vector_type(8))) unsigned short u16x8;

static __device__ __forceinline__ unsigned short f2bf(float f) {
  unsigned int u = __builtin_bit_cast(unsigned int, f);
  u += 0x7fffu + ((u >> 16) & 1u);
  return (unsigned short)(u >> 16);
}
static __device__ __forceinline__ unsigned int pk2(float lo, float hi) {
  return (unsigned int)f2bf(lo) | ((unsigned int)f2bf(hi) << 16);
}
static __device__ __forceinline__ void gload_lds16(const void* g, void* l) {
  __builtin_amdgcn_global_load_lds(
      (__attribute__((address_space(1))) void*)(g),
      (__attribute__((address_space(3))) void*)(l), 16, 0, 0);
}

// ---------- f32 -> bf16 bulk convert ----------
__global__ __launch_bounds__(256) void cvt_bf16(const float* __restrict__ in,
                                                unsigned short* __restrict__ out,
                                                long n8) {
  const long stride = (long)gridDim.x * 256;
  for (long i = (long)blockIdx.x * 256 + threadIdx.x; i < n8; i += stride) {
    const float4 a = ((const float4*)in)[2 * i];
    const float4 b = ((const float4*)in)[2 * i + 1];
    uint4 w;
    w.x = pk2(a.x, a.y);
    w.y = pk2(a.z, a.w);
    w.z = pk2(b.x, b.y);
    w.w = pk2(b.z, b.w);
    ((uint4*)out)[i] = w;
  }
}

// ---------- fused transpose of 4 weight mats: f32 (K x N) -> bf16 (N x K) ----------
__global__ __launch_bounds__(256) void transpose_all(
    const float* __restrict__ Wq, const float* __restrict__ Wk,
    const float* __restrict__ Wv, const float* __restrict__ Wo,
    unsigned short* __restrict__ wqT, unsigned short* __restrict__ wkvT,
    unsigned short* __restrict__ woT) {
  __shared__ float tile[64][65];
  const int z = blockIdx.z;
  const float* W = (z == 0) ? Wq : (z == 1) ? Wk : (z == 2) ? Wv : Wo;
  unsigned short* WT = (z == 0) ? wqT : (z == 1) ? wkvT : (z == 2) ? (wkvT + 1024 * 1024) : woT;
  const int bx = blockIdx.x;
  const int by = blockIdx.y;
  const int t = threadIdx.x;
  const int rr = t >> 6;
  const int cc = t & 63;
#pragma unroll
  for (int i = 0; i < 16; ++i) {
    int r = i * 4 + rr;
    tile[r][cc] = W[(size_t)(by * 64 + r) * 1024 + bx * 64 + cc];
  }
  __syncthreads();
#pragma unroll
  for (int i = 0; i < 16; ++i) {
    int n = i * 4 + rr;
    WT[(size_t)(bx * 64 + n) * 1024 + by * 64 + cc] = f2bf(tile[cc][n]);
  }
}

// ---------- LayerNorm of h[b, t+63] -> x[b, t] (bf16), pad rows t>=1985 zero ----------
__global__ __launch_bounds__(256) void ln_kernel(const float* __restrict__ H,
                                                 const float* __restrict__ gamma,
                                                 const float* __restrict__ beta,
                                                 unsigned short* __restrict__ X) {
  const int row = blockIdx.x;
  const int b = row >> 11;
  const int t = row & 2047;
  const int tid = threadIdx.x;
  uint2* xo = (uint2*)(X + (size_t)row * 1024);
  if (t >= 1985) {
    uint2 z;
    z.x = 0;
    z.y = 0;
    xo[tid] = z;
    return;
  }
  const float4* hp = (const float4*)(H + (size_t)(b * 2048 + t + 63) * 1024);
  float4 v = hp[tid];
  float s = v.x + v.y + v.z + v.w;
  float q = v.x * v.x + v.y * v.y + v.z * v.z + v.w * v.w;
#pragma unroll
  for (int off = 32; off > 0; off >>= 1) {
    s += __shfl_down(s, off);
    q += __shfl_down(q, off);
  }
  __shared__ float red[8];
  const int lane = tid & 63, wid = tid >> 6;
  if (lane == 0) {
    red[wid] = s;
    red[4 + wid] = q;
  }
  __syncthreads();
  s = red[0] + red[1] + red[2] + red[3];
  q = red[4] + red[5] + red[6] + red[7];
  const float mu = s * (1.0f / 1024.0f);
  const float var = q * (1.0f / 1024.0f) - mu * mu;
  const float rs = rsqrtf(var + 1e-5f);
  const float4 g = ((const float4*)gamma)[tid];
  const float4 bb = ((const float4*)beta)[tid];
  uint2 w;
  w.x = pk2((v.x - mu) * rs * g.x + bb.x, (v.y - mu) * rs * g.y + bb.y);
  w.y = pk2((v.z - mu) * rs * g.z + bb.z, (v.w - mu) * rs * g.w + bb.w);
  xo[tid] = w;
}

// ---------- copy rows t<63 of each batch: out = h ----------
__global__ __launch_bounds__(256) void fill_head(const float* __restrict__ H,
                                                 float* __restrict__ OUT) {
  const int idx = blockIdx.x * 256 + threadIdx.x;
  const int b = idx / 16128;
  const int rem = idx - b * 16128;
  const size_t off = (size_t)b * 524288 + rem;
  ((float4*)OUT)[off] = ((const float4*)H)[off];
}

// ====== 256x256 8-phase GEMM: R4 skeleton + ALL frag reads hoisted to P1 ======
// 512 threads = 8 waves (2M x 4N), per-wave 128x64 output; BK=64, 16 k-tiles.
// LDS: 2 dbuf x 4 slots {A0,A1,B0,B1}, slot = 128 rows x 64 k (16KB). 128 KiB.
// KEY: all 24 fragment ds_read_b128 for tile t issue in P1 BEFORE the mid-bar;
// the LDS pipe drains them underneath P1-P4's MFMA clusters (compiler emits
// counted per-use lgkmcnt waits). Stages: t+1 slots 1,2,3 at P1,P2,P3 (->buf^1),
// t+2 slot0 at P4 (->buf); vmcnt(2) at P4 only. Never drains to 0 in the loop.
// Hazards (vs R4, proven): read placement is earlier within the same tile and
// same buffer - no cross-wave ordering change. slot0's last reader (ax) retires
// via lgkm before P3's MMA, i.e. before the P3-end barrier; P4's stage into
// slot0 issues after it.
#define BAR()                                 \
  {                                           \
    asm volatile("" ::: "memory");            \
    __builtin_amdgcn_s_barrier();             \
    __builtin_amdgcn_sched_barrier(0);        \
  }
#define VMW2() asm volatile("s_waitcnt vmcnt(2)" ::: "memory")

#define LDA_(dst, mh, buf)                                                              \
  {                                                                                     \
    const char* base_ = (const char*)&lds[buf][wm][0];                                  \
    _Pragma("unroll") for (int mi = 0; mi < 4; ++mi) {                                  \
      const int r_ = (mh) * 64 + mi * 16 + lrow;                                        \
      dst[mi][0] = *(const bf16x8*)(base_ + r_ * 128 + (((0 + lk) ^ (r_ & 7)) * 16));   \
      dst[mi][1] = *(const bf16x8*)(base_ + r_ * 128 + (((4 + lk) ^ (r_ & 7)) * 16));   \
    }                                                                                   \
  }
#define LDB_(dst, nh, buf)                                                              \
  {                                                                                     \
    const char* base_ = (const char*)&lds[buf][2 + (wn >> 1)][0];                       \
    _Pragma("unroll") for (int ni = 0; ni < 2; ++ni) {                                  \
      const int r_ = (wn & 1) * 64 + (nh) * 32 + ni * 16 + lrow;                        \
      dst[ni][0] = *(const bf16x8*)(base_ + r_ * 128 + (((0 + lk) ^ (r_ & 7)) * 16));   \
      dst[ni][1] = *(const bf16x8*)(base_ + r_ * 128 + (((4 + lk) ^ (r_ & 7)) * 16));   \
    }                                                                                   \
  }
#define MMA_(mh, nh, A, B)                                                              \
  {                                                                                     \
    __builtin_amdgcn_s_setprio(1);                                                      \
    _Pragma("unroll") for (int mi = 0; mi < 4; ++mi)                                    \
        _Pragma("unroll") for (int ni = 0; ni < 2; ++ni) {                              \
      acc[(mh) * 4 + mi][(nh) * 2 + ni] = __builtin_amdgcn_mfma_f32_16x16x32_bf16(      \
          A[mi][0], B[ni][0], acc[(mh) * 4 + mi][(nh) * 2 + ni], 0, 0, 0);              \
      acc[(mh) * 4 + mi][(nh) * 2 + ni] = __builtin_amdgcn_mfma_f32_16x16x32_bf16(      \
          A[mi][1], B[ni][1], acc[(mh) * 4 + mi][(nh) * 2 + ni], 0, 0, 0);              \
    }                                                                                   \
    __builtin_amdgcn_s_setprio(0);                                                      \
  }
#define TILE(tt, BUF)                         \
  {                                           \
    /* P1: ALL fragment reads for this tile */\
    LDA_(af, 0, BUF);                         \
    LDB_(b0, 0, BUF);                         \
    LDB_(b1, 1, BUF);                         \
    LDA_(ax, 1, BUF);                         \
    STAGE(BUF ^ 1, 1, (tt) + 1);              \
    BAR();                                    \
    MMA_(0, 0, af, b0);                       \
    BAR();                                    \
    /* P2 */                                  \
    STAGE(BUF ^ 1, 2, (tt) + 1);              \
    MMA_(0, 1, af, b1);                       \
    BAR();                                    \
    /* P3 */                                  \
    STAGE(BUF ^ 1, 3, (tt) + 1);              \
    MMA_(1, 1, ax, b1);                       \
    BAR();                                    \
    /* P4: stage slot0(t+2) into this buf; counted drain */ \
    STAGE(BUF, 0, (tt) + 2);                  \
    MMA_(1, 0, ax, b0);                       \
    VMW2();                                   \
    BAR();                                    \
  }

template <int MODE>
__global__ __launch_bounds__(512, 2) void gemm256(
    const unsigned short* __restrict__ A, const unsigned short* __restrict__ BT,
    const float* __restrict__ bias1, const float* __restrict__ bias2,
    unsigned short* __restrict__ C1, unsigned short* __restrict__ C2,
    const float* __restrict__ H, float* __restrict__ OUT) {
  __shared__ alignas(16) unsigned short lds[2][4][128 * 64];
  const int tid = threadIdx.x;
  const int lane = tid & 63;
  const int wid = tid >> 6;
  const int wm = wid >> 2, wn = wid & 3;
  const int lrow = lane & 15, lk = lane >> 4;

  const int nx = gridDim.x;
  const int orig = blockIdx.y * nx + blockIdx.x;
  const int cpx = (nx * gridDim.y) >> 3;
  const int swz = (orig & 7) * cpx + (orig >> 3);
  const int m0 = (swz / nx) * 256;
  const int n0 = (swz % nx) * 256;

  f32x4 acc[8][4] = {};
  bf16x8 af[4][2], ax[4][2], b0[2][2], b1[2][2];

  auto STAGE = [&](int buf, int slot, int kt) {
    const int kc = kt < 16 ? kt : 15;
    const unsigned short* src = (slot < 2) ? A + (size_t)(m0 + slot * 128) * 1024
                                           : BT + (size_t)(n0 + (slot - 2) * 128) * 1024;
    unsigned short* dst = &lds[buf][slot][0];
#pragma unroll
    for (int l = 0; l < 2; ++l) {
      const int row = l * 64 + wid * 8 + (lane >> 3);
      const int ch = (lane & 7) ^ (row & 7);
      gload_lds16(src + (size_t)row * 1024 + kc * 64 + ch * 8,
                  (char*)dst + (l * 64 + wid * 8) * 128);
    }
  };

  // prologue: tile0 (4 slots, 8 loads) + slot0(tile1) (2); retire tile0, keep 2.
  STAGE(0, 0, 0);
  STAGE(0, 1, 0);
  STAGE(0, 2, 0);
  STAGE(0, 3, 0);
  STAGE(1, 0, 1);
  VMW2();
  __builtin_amdgcn_s_barrier();

  for (int it = 0; it < 8; ++it) {
    const int t = 2 * it;
    TILE(t, 0);
    TILE(t + 1, 1);
  }
  asm volatile("s_waitcnt vmcnt(0)" ::: "memory");
  __syncthreads();

  if (MODE == 0) {
    // ---- LDS-bounce epilogue: coalesced bf16 stores ----
    const float* bsel = (n0 < 1024) ? bias1 : bias2;
    const int cbase = (n0 < 1024) ? n0 : (n0 - 1024);
    unsigned short* Cp0 = (n0 < 1024) ? C1 : C2;
    float bsv[4];
#pragma unroll
    for (int N = 0; N < 4; ++N) bsv[N] = bsel[cbase + wn * 64 + N * 16 + lrow];
    float* arr = (float*)&lds[0][0][0];  // [64][260] padded f32
    const int q4 = lane >> 4;
#pragma unroll
    for (int p = 0; p < 4; ++p) {
      if (wm == (p >> 1)) {
#pragma unroll
        for (int mb = 0; mb < 4; ++mb) {
          const int M = (p & 1) * 4 + mb;
#pragma unroll
          for (int N = 0; N < 4; ++N) {
            const int cl = wn * 64 + N * 16 + lrow;
#pragma unroll
            for (int r = 0; r < 4; ++r) {
              arr[(mb * 16 + q4 * 4 + r) * 260 + cl] = acc[M][N][r] + bsv[N];
            }
          }
        }
      }
      __syncthreads();
#pragma unroll
      for (int k = 0; k < 4; ++k) {
        const int chunk = k * 512 + tid;
        const int row = chunk >> 5;
        const int c8 = chunk & 31;
        const float* s = arr + row * 260 + c8 * 8;
        float4 f0 = *(const float4*)(s);
        float4 f1 = *(const float4*)(s + 4);
        uint4 w;
        w.x = pk2(f0.x, f0.y);
        w.y = pk2(f0.z, f0.w);
        w.z = pk2(f1.x, f1.y);
        w.w = pk2(f1.z, f1.w);
        *(uint4*)(Cp0 + (size_t)(m0 + p * 64 + row) * 1024 + cbase + c8 * 8) = w;
      }
      __syncthreads();
    }
  } else {
    const int r0 = lane >> 4;
#pragma unroll
    for (int N = 0; N < 4; ++N) {
      const int col = n0 + wn * 64 + N * 16 + lrow;
      const float bsv = bias1[col];
#pragma unroll
      for (int M = 0; M < 8; ++M) {
        const int row = m0 + wm * 128 + M * 16 + r0 * 4;
#pragma unroll
        for (int r = 0; r < 4; ++r) {
          const int gr = row + r;
          if ((gr & 2047) < 1985) {
            const size_t idx = (size_t)(gr + 63) * 1024 + col;
            OUT[idx] = H[idx] + acc[M][N][r] + bsv;
          }
        }
      }
    }
  }
}

// ---------- attention per (b,c,h): 64 queries x 256 keys ----------
__global__ __launch_bounds__(256) void attn_kernel(
    const unsigned short* __restrict__ Q, const unsigned short* __restrict__ K,
    const unsigned short* __restrict__ V, unsigned short* __restrict__ O) {
  __shared__ alignas(16) unsigned short k_lds[256 * 64];
  __shared__ alignas(16) unsigned short v_t[64 * 256];
  // chunked XCD swizzle: all 16 heads of one (b,c) land on one XCD (KV L2 reuse)
  const int w = ((blockIdx.x & 7) << 9) | (blockIdx.x >> 3);
  const int h = w & 15;
  const int bc = w >> 4;
  const int tid = threadIdx.x;
  const int lane = tid & 63;
  const int wid = tid >> 6;
  const size_t kv0 = (size_t)bc * 256 * 1024 + h * 64;

  bf16x8 qf[2];
  {
    const size_t qrow = (size_t)bc * 64 + wid * 16 + (lane & 15);
    const unsigned short* qp = Q + qrow * 1024 + h * 64 + (lane >> 4) * 8;
    qf[0] = *(const bf16x8*)(qp);
    qf[1] = *(const bf16x8*)(qp + 32);
  }
#pragma unroll
  for (int it = 0; it < 8; ++it) {
    const int j = it * 32 + (tid >> 3);
    const int c = tid & 7;
    const uint4 kv = *(const uint4*)(K + kv0 + (size_t)j * 1024 + c * 8);
    *(uint4*)((char*)k_lds + j * 128 + ((c ^ (j & 7)) * 16)) = kv;
  }
  {
    const int j = (tid >> 1) * 2;
    const int half = tid & 1;
#pragma unroll
    for (int cc2 = 0; cc2 < 4; ++cc2) {
      const int chunk = half * 4 + cc2;
      const int d0 = chunk * 8;
      u16x8 a = *(const u16x8*)(V + kv0 + (size_t)j * 1024 + d0);
      u16x8 b = *(const u16x8*)(V + kv0 + (size_t)(j + 1) * 1024 + d0);
#pragma unroll
      for (int dd = 0; dd < 8; ++dd) {
        const int d = d0 + dd;
        unsigned int p = (unsigned int)a[dd] | ((unsigned int)b[dd] << 16);
        *(unsigned int*)((char*)v_t + d * 512 + (((j >> 3) ^ (d & 7)) * 16) + ((j & 7) * 2)) = p;
      }
    }
  }
  __syncthreads();

  f32x4 accs[16] = {};
#pragma unroll
  for (int jt = 0; jt < 16; ++jt) {
#pragma unroll
    for (int ks = 0; ks < 2; ++ks) {
      const int r = jt * 16 + (lane & 15);
      bf16x8 kf = *(const bf16x8*)((const char*)k_lds + r * 128 +
                                   (((ks * 4 + (lane >> 4)) ^ (r & 7)) * 16));
      accs[jt] = __builtin_amdgcn_mfma_f32_16x16x32_bf16(qf[ks], kf, accs[jt], 0, 0, 0);
    }
  }
  __syncthreads();

  float inv_[4];
#pragma unroll
  for (int r = 0; r < 4; ++r) {
    float m = accs[0][r];
#pragma unroll
    for (int jt = 1; jt < 16; ++jt) m = fmaxf(m, accs[jt][r]);
#pragma unroll
    for (int mk = 1; mk < 16; mk <<= 1) m = fmaxf(m, __shfl_xor(m, mk));
    float s = 0.f;
#pragma unroll
    for (int jt = 0; jt < 16; ++jt) {
      float p = __expf((accs[jt][r] - m) * 0.125f);
      accs[jt][r] = p;
      s += p;
    }
#pragma unroll
    for (int mk = 1; mk < 16; mk <<= 1) s += __shfl_xor(s, mk);
    inv_[r] = 1.0f / s;
  }
  char* pbase = (char*)k_lds + wid * 8192;
  {
    const int jc = lane & 15;
    const int i0 = (lane >> 4) * 4;
#pragma unroll
    for (int jt = 0; jt < 16; ++jt) {
      const int j = jt * 16 + jc;
#pragma unroll
      for (int r = 0; r < 4; ++r) {
        const int i = i0 + r;
        *(unsigned short*)(pbase + i * 512 + (((j >> 3) ^ (i & 7)) * 16) + ((j & 7) * 2)) =
            f2bf(accs[jt][r] * inv_[r]);
      }
    }
  }
  __syncthreads();

  f32x4 acco[4] = {};
#pragma unroll
  for (int jb = 0; jb < 8; ++jb) {
    const int i = lane & 15;
    bf16x8 pf = *(const bf16x8*)(pbase + i * 512 + (((jb * 4 + (lane >> 4)) ^ (i & 7)) * 16));
#pragma unroll
    for (int ni = 0; ni < 4; ++ni) {
      const int d = ni * 16 + (lane & 15);
      bf16x8 vf = *(const bf16x8*)((const char*)v_t + d * 512 +
                                   (((jb * 4 + (lane >> 4)) ^ (d & 7)) * 16));
      acco[ni] = __builtin_amdgcn_mfma_f32_16x16x32_bf16(pf, vf, acco[ni], 0, 0, 0);
    }
  }
  {
    const size_t row0 = (size_t)bc * 64 + wid * 16 + (lane >> 4) * 4;
#pragma unroll
    for (int ni = 0; ni < 4; ++ni) {
      const int col = h * 64 + ni * 16 + (lane & 15);
#pragma unroll
      for (int r = 0; r < 4; ++r) {
        O[(row0 + r) * 1024 + col] = f2bf(acco[ni][r]);
      }
    }
  }
}

extern "C" void kernel_launch(void* const* d_in, const int* in_sizes, int n_in,
                              void* d_out, int out_size, void* d_ws, size_t ws_size,
                              hipStream_t stream) {
  const float* h = (const float*)d_in[0];
  const float* e = (const float*)d_in[1];
  const float* Wq = (const float*)d_in[2];
  const float* bq = (const float*)d_in[3];
  const float* Wk = (const float*)d_in[4];
  const float* bk = (const float*)d_in[5];
  const float* Wv = (const float*)d_in[6];
  const float* bv = (const float*)d_in[7];
  const float* gamma = (const float*)d_in[8];
  const float* beta = (const float*)d_in[9];
  const float* Wo = (const float*)d_in[10];
  const float* bo = (const float*)d_in[11];
  float* out = (float*)d_out;

  char* ws = (char*)d_ws;
  unsigned short* x = (unsigned short*)ws;                        // 32MB (reused as o)
  unsigned short* q = (unsigned short*)(ws + (32ull << 20));      // 32MB
  unsigned short* kbuf = (unsigned short*)(ws + (64ull << 20));   // 128MB
  unsigned short* vbuf = (unsigned short*)(ws + (192ull << 20));  // 128MB
  unsigned short* ebf = (unsigned short*)(ws + (320ull << 20));   // 128MB
  unsigned short* wqT = (unsigned short*)(ws + (448ull << 20));   // 2MB
  unsigned short* wkvT = (unsigned short*)(ws + (450ull << 20));  // 4MB
  unsigned short* woT = (unsigned short*)(ws + (454ull << 20));   // 2MB
  unsigned short* o = x;

  dim3 tb(256);
  cvt_bf16<<<2048, tb, 0, stream>>>(e, ebf, 8388608L);
  transpose_all<<<dim3(16, 16, 4), tb, 0, stream>>>(Wq, Wk, Wv, Wo, wqT, wkvT, woT);
  ln_kernel<<<16384, tb, 0, stream>>>(h, gamma, beta, x);
  // Q = x @ Wq + bq
  gemm256<0><<<dim3(4, 64), dim3(512), 0, stream>>>(x, wqT, bq, nullptr, q, nullptr,
                                                    nullptr, nullptr);
  // [K|V] = e @ [Wk|Wv] + [bk|bv]
  gemm256<0><<<dim3(8, 256), dim3(512), 0, stream>>>(ebf, wkvT, bk, bv, kbuf, vbuf,
                                                     nullptr, nullptr);
  // attention
  attn_kernel<<<4096, tb, 0, stream>>>(q, kbuf, vbuf, o);
  // rows t<63: out = h
  fill_head<<<504, tb, 0, stream>>>(h, out);
  // rows t>=63: out = h + shift63(o @ Wo + bo)
  gemm256<1><<<dim3(4, 64), dim3(512), 0, stream>>>(o, woT, bo, nullptr, nullptr, nullptr,
                                                    h, out);
}

// Round 10
// 561.918 us; speedup vs baseline: 1.1905x; 1.1905x over previous
//
#include <hip/hip_runtime.h>
#include <hip/hip_bf16.h>

typedef __attribute__((ext_vector_type(8))) short bf16x8;
typedef __attribute__((ext_vector_type(4))) float f32x4;
typedef __attribute__((ext_vector_type(8))) unsigned short u16x8;

static __device__ __forceinline__ unsigned short f2bf(float f) {
  unsigned int u = __builtin_bit_cast(unsigned int, f);
  u += 0x7fffu + ((u >> 16) & 1u);
  return (unsigned short)(u >> 16);
}
static __device__ __forceinline__ unsigned int pk2(float lo, float hi) {
  return (unsigned int)f2bf(lo) | ((unsigned int)f2bf(hi) << 16);
}
static __device__ __forceinline__ void gload_lds16(const void* g, void* l) {
  __builtin_amdgcn_global_load_lds(
      (__attribute__((address_space(1))) void*)(g),
      (__attribute__((address_space(3))) void*)(l), 16, 0, 0);
}

// ---------- f32 -> bf16 bulk convert ----------
__global__ __launch_bounds__(256) void cvt_bf16(const float* __restrict__ in,
                                                unsigned short* __restrict__ out,
                                                long n8) {
  const long stride = (long)gridDim.x * 256;
  for (long i = (long)blockIdx.x * 256 + threadIdx.x; i < n8; i += stride) {
    const float4 a = ((const float4*)in)[2 * i];
    const float4 b = ((const float4*)in)[2 * i + 1];
    uint4 w;
    w.x = pk2(a.x, a.y);
    w.y = pk2(a.z, a.w);
    w.z = pk2(b.x, b.y);
    w.w = pk2(b.z, b.w);
    ((uint4*)out)[i] = w;
  }
}

// ---------- fused transpose of 4 weight mats: f32 (K x N) -> bf16 (N x K) ----------
__global__ __launch_bounds__(256) void transpose_all(
    const float* __restrict__ Wq, const float* __restrict__ Wk,
    const float* __restrict__ Wv, const float* __restrict__ Wo,
    unsigned short* __restrict__ wqT, unsigned short* __restrict__ wkvT,
    unsigned short* __restrict__ woT) {
  __shared__ float tile[64][65];
  const int z = blockIdx.z;
  const float* W = (z == 0) ? Wq : (z == 1) ? Wk : (z == 2) ? Wv : Wo;
  unsigned short* WT = (z == 0) ? wqT : (z == 1) ? wkvT : (z == 2) ? (wkvT + 1024 * 1024) : woT;
  const int bx = blockIdx.x;
  const int by = blockIdx.y;
  const int t = threadIdx.x;
  const int rr = t >> 6;
  const int cc = t & 63;
#pragma unroll
  for (int i = 0; i < 16; ++i) {
    int r = i * 4 + rr;
    tile[r][cc] = W[(size_t)(by * 64 + r) * 1024 + bx * 64 + cc];
  }
  __syncthreads();
#pragma unroll
  for (int i = 0; i < 16; ++i) {
    int n = i * 4 + rr;
    WT[(size_t)(bx * 64 + n) * 1024 + by * 64 + cc] = f2bf(tile[cc][n]);
  }
}

// ---------- LayerNorm of h[b, t+63] -> x[b, t] (bf16), pad rows t>=1985 zero ----------
__global__ __launch_bounds__(256) void ln_kernel(const float* __restrict__ H,
                                                 const float* __restrict__ gamma,
                                                 const float* __restrict__ beta,
                                                 unsigned short* __restrict__ X) {
  const int row = blockIdx.x;
  const int b = row >> 11;
  const int t = row & 2047;
  const int tid = threadIdx.x;
  uint2* xo = (uint2*)(X + (size_t)row * 1024);
  if (t >= 1985) {
    uint2 z;
    z.x = 0;
    z.y = 0;
    xo[tid] = z;
    return;
  }
  const float4* hp = (const float4*)(H + (size_t)(b * 2048 + t + 63) * 1024);
  float4 v = hp[tid];
  float s = v.x + v.y + v.z + v.w;
  float q = v.x * v.x + v.y * v.y + v.z * v.z + v.w * v.w;
#pragma unroll
  for (int off = 32; off > 0; off >>= 1) {
    s += __shfl_down(s, off);
    q += __shfl_down(q, off);
  }
  __shared__ float red[8];
  const int lane = tid & 63, wid = tid >> 6;
  if (lane == 0) {
    red[wid] = s;
    red[4 + wid] = q;
  }
  __syncthreads();
  s = red[0] + red[1] + red[2] + red[3];
  q = red[4] + red[5] + red[6] + red[7];
  const float mu = s * (1.0f / 1024.0f);
  const float var = q * (1.0f / 1024.0f) - mu * mu;
  const float rs = rsqrtf(var + 1e-5f);
  const float4 g = ((const float4*)gamma)[tid];
  const float4 bb = ((const float4*)beta)[tid];
  uint2 w;
  w.x = pk2((v.x - mu) * rs * g.x + bb.x, (v.y - mu) * rs * g.y + bb.y);
  w.y = pk2((v.z - mu) * rs * g.z + bb.z, (v.w - mu) * rs * g.w + bb.w);
  xo[tid] = w;
}

// ---------- copy rows t<63 of each batch: out = h ----------
__global__ __launch_bounds__(256) void fill_head(const float* __restrict__ H,
                                                 float* __restrict__ OUT) {
  const int idx = blockIdx.x * 256 + threadIdx.x;
  const int b = idx / 16128;
  const int rem = idx - b * 16128;
  const size_t off = (size_t)b * 524288 + rem;
  ((float4*)OUT)[off] = ((const float4*)H)[off];
}

// ================= 256x256 8-phase GEMM (T2+T3+T4+T5) — R4 proven =================
// 512 threads = 8 waves (2M x 4N), per-wave 128x64 output; BK=64, 16 k-tiles.
// LDS: 2 dbuf x 4 slots {A0,A1,B0,B1}, slot = 128 x 64 (16KB). 128 KiB.
// Per 2-tile iter: 8 phases, 1 slot staged/phase, vmcnt(2) at P4/P8 only.
// B fragments for BOTH n-halves held in regs across the 4 phases (no reread);
// P4/P8 are pure-MFMA. Barriers: fence + s_barrier + sched_barrier(0) --
// NO forced lgkmcnt(0) drain (compiler emits per-use counted waits).
#define FENCE_BAR()                                  \
  {                                                  \
    asm volatile("" ::: "memory");                   \
    __builtin_amdgcn_s_barrier();                    \
    __builtin_amdgcn_sched_barrier(0);               \
  }
#define VMW2() asm volatile("s_waitcnt vmcnt(2)" ::: "memory")

#define LDA_(mh, buf)                                                                   \
  {                                                                                     \
    const char* base_ = (const char*)&lds[buf][wm][0];                                  \
    _Pragma("unroll") for (int mi = 0; mi < 4; ++mi) {                                  \
      const int r_ = (mh) * 64 + mi * 16 + lrow;                                        \
      af[mi][0] = *(const bf16x8*)(base_ + r_ * 128 + (((0 + lk) ^ (r_ & 7)) * 16));    \
      af[mi][1] = *(const bf16x8*)(base_ + r_ * 128 + (((4 + lk) ^ (r_ & 7)) * 16));    \
    }                                                                                   \
  }
#define LDB_(nh, buf)                                                                   \
  {                                                                                     \
    const char* base_ = (const char*)&lds[buf][2 + (wn >> 1)][0];                       \
    _Pragma("unroll") for (int ni = 0; ni < 2; ++ni) {                                  \
      const int r_ = (wn & 1) * 64 + (nh) * 32 + ni * 16 + lrow;                        \
      bfr[nh][ni][0] =                                                                  \
          *(const bf16x8*)(base_ + r_ * 128 + (((0 + lk) ^ (r_ & 7)) * 16));            \
      bfr[nh][ni][1] =                                                                  \
          *(const bf16x8*)(base_ + r_ * 128 + (((4 + lk) ^ (r_ & 7)) * 16));            \
    }                                                                                   \
  }
#define MMA_(mh, nh)                                                                    \
  {                                                                                     \
    __builtin_amdgcn_s_setprio(1);                                                      \
    _Pragma("unroll") for (int mi = 0; mi < 4; ++mi)                                    \
        _Pragma("unroll") for (int ni = 0; ni < 2; ++ni) {                              \
      acc[(mh) * 4 + mi][(nh) * 2 + ni] = __builtin_amdgcn_mfma_f32_16x16x32_bf16(      \
          af[mi][0], bfr[nh][ni][0], acc[(mh) * 4 + mi][(nh) * 2 + ni], 0, 0, 0);       \
      acc[(mh) * 4 + mi][(nh) * 2 + ni] = __builtin_amdgcn_mfma_f32_16x16x32_bf16(      \
          af[mi][1], bfr[nh][ni][1], acc[(mh) * 4 + mi][(nh) * 2 + ni], 0, 0, 0);       \
    }                                                                                   \
    __builtin_amdgcn_s_setprio(0);                                                      \
  }

template <int MODE>
__global__ __launch_bounds__(512, 2) void gemm256(
    const unsigned short* __restrict__ A, const unsigned short* __restrict__ BT,
    const float* __restrict__ bias1, const float* __restrict__ bias2,
    unsigned short* __restrict__ C1, unsigned short* __restrict__ C2,
    const float* __restrict__ H, float* __restrict__ OUT) {
  __shared__ alignas(16) unsigned short lds[2][4][128 * 64];
  const int tid = threadIdx.x;
  const int lane = tid & 63;
  const int wid = tid >> 6;
  const int wm = wid >> 2, wn = wid & 3;
  const int lrow = lane & 15, lk = lane >> 4;

  const int nx = gridDim.x;
  const int orig = blockIdx.y * nx + blockIdx.x;
  const int cpx = (nx * gridDim.y) >> 3;
  const int swz = (orig & 7) * cpx + (orig >> 3);
  const int m0 = (swz / nx) * 256;
  const int n0 = (swz % nx) * 256;

  f32x4 acc[8][4] = {};
  bf16x8 af[4][2], bfr[2][2][2];

  auto STAGE = [&](int slot, int kt) {
    const int buf = kt & 1;
    const int kc = kt < 16 ? kt : 15;
    const unsigned short* src = (slot < 2) ? A + (size_t)(m0 + slot * 128) * 1024
                                           : BT + (size_t)(n0 + (slot - 2) * 128) * 1024;
    unsigned short* dst = &lds[buf][slot][0];
#pragma unroll
    for (int l = 0; l < 2; ++l) {
      const int row = l * 64 + wid * 8 + (lane >> 3);
      const int ch = (lane & 7) ^ (row & 7);
      gload_lds16(src + (size_t)row * 1024 + kc * 64 + ch * 8,
                  (char*)dst + (l * 64 + wid * 8) * 128);
    }
  };

  // prologue: tile0 (4 slots) + tile1.A0; drain tile0
  STAGE(0, 0);
  STAGE(1, 0);
  STAGE(2, 0);
  STAGE(3, 0);
  STAGE(0, 1);
  VMW2();
  __builtin_amdgcn_s_barrier();

  for (int it = 0; it < 8; ++it) {
    const int t = 2 * it;
    // P1
    LDA_(0, 0);
    LDB_(0, 0);
    STAGE(1, t + 1);
    FENCE_BAR();
    MMA_(0, 0);
    FENCE_BAR();
    // P2
    LDB_(1, 0);
    STAGE(2, t + 1);
    FENCE_BAR();
    MMA_(0, 1);
    FENCE_BAR();
    // P3
    LDA_(1, 0);
    STAGE(3, t + 1);
    FENCE_BAR();
    MMA_(1, 1);
    FENCE_BAR();
    // P4: pure MFMA (bfr[0] held from P1); vmcnt(2) drains tile t+1 slots
    STAGE(0, t + 2);
    FENCE_BAR();
    MMA_(1, 0);
    VMW2();
    FENCE_BAR();
    // P5
    LDA_(0, 1);
    LDB_(0, 1);
    STAGE(1, t + 2);
    FENCE_BAR();
    MMA_(0, 0);
    FENCE_BAR();
    // P6
    LDB_(1, 1);
    STAGE(2, t + 2);
    FENCE_BAR();
    MMA_(0, 1);
    FENCE_BAR();
    // P7
    LDA_(1, 1);
    STAGE(3, t + 2);
    FENCE_BAR();
    MMA_(1, 1);
    FENCE_BAR();
    // P8: pure MFMA; vmcnt(2) drains tile t+2 slots
    STAGE(0, t + 3);
    FENCE_BAR();
    MMA_(1, 0);
    VMW2();
    FENCE_BAR();
  }
  // drain any in-flight clamped stages before reusing LDS in the epilogue
  asm volatile("s_waitcnt vmcnt(0)" ::: "memory");
  __syncthreads();

  if (MODE == 0) {
    // ---- LDS-bounce epilogue: coalesced bf16 stores ----
    const float* bsel = (n0 < 1024) ? bias1 : bias2;
    const int cbase = (n0 < 1024) ? n0 : (n0 - 1024);
    unsigned short* Cp0 = (n0 < 1024) ? C1 : C2;
    float bsv[4];
#pragma unroll
    for (int N = 0; N < 4; ++N) bsv[N] = bsel[cbase + wn * 64 + N * 16 + lrow];
    float* arr = (float*)&lds[0][0][0];  // [64][260] padded f32
    const int q4 = lane >> 4;
#pragma unroll
    for (int p = 0; p < 4; ++p) {
      if (wm == (p >> 1)) {
#pragma unroll
        for (int mb = 0; mb < 4; ++mb) {
          const int M = (p & 1) * 4 + mb;
#pragma unroll
          for (int N = 0; N < 4; ++N) {
            const int cl = wn * 64 + N * 16 + lrow;
#pragma unroll
            for (int r = 0; r < 4; ++r) {
              arr[(mb * 16 + q4 * 4 + r) * 260 + cl] = acc[M][N][r] + bsv[N];
            }
          }
        }
      }
      __syncthreads();
#pragma unroll
      for (int k = 0; k < 4; ++k) {
        const int chunk = k * 512 + tid;
        const int row = chunk >> 5;
        const int c8 = chunk & 31;
        const float* s = arr + row * 260 + c8 * 8;
        float4 f0 = *(const float4*)(s);
        float4 f1 = *(const float4*)(s + 4);
        uint4 w;
        w.x = pk2(f0.x, f0.y);
        w.y = pk2(f0.z, f0.w);
        w.z = pk2(f1.x, f1.y);
        w.w = pk2(f1.z, f1.w);
        *(uint4*)(Cp0 + (size_t)(m0 + p * 64 + row) * 1024 + cbase + c8 * 8) = w;
      }
      __syncthreads();
    }
  } else {
    const int r0 = lane >> 4;
#pragma unroll
    for (int N = 0; N < 4; ++N) {
      const int col = n0 + wn * 64 + N * 16 + lrow;
      const float bsv = bias1[col];
#pragma unroll
      for (int M = 0; M < 8; ++M) {
        const int row = m0 + wm * 128 + M * 16 + r0 * 4;
#pragma unroll
        for (int r = 0; r < 4; ++r) {
          const int gr = row + r;
          if ((gr & 2047) < 1985) {
            const size_t idx = (size_t)(gr + 63) * 1024 + col;
            OUT[idx] = H[idx] + acc[M][N][r] + bsv;
          }
        }
      }
    }
  }
}

// ---------- attention per (b,c,h): 64 queries x 256 keys ----------
__global__ __launch_bounds__(256) void attn_kernel(
    const unsigned short* __restrict__ Q, const unsigned short* __restrict__ K,
    const unsigned short* __restrict__ V, unsigned short* __restrict__ O) {
  __shared__ alignas(16) unsigned short k_lds[256 * 64];
  __shared__ alignas(16) unsigned short v_t[64 * 256];
  // chunked XCD swizzle: all 16 heads of one (b,c) land on one XCD (KV L2 reuse)
  const int w = ((blockIdx.x & 7) << 9) | (blockIdx.x >> 3);
  const int h = w & 15;
  const int bc = w >> 4;
  const int tid = threadIdx.x;
  const int lane = tid & 63;
  const int wid = tid >> 6;
  const size_t kv0 = (size_t)bc * 256 * 1024 + h * 64;

  bf16x8 qf[2];
  {
    const size_t qrow = (size_t)bc * 64 + wid * 16 + (lane & 15);
    const unsigned short* qp = Q + qrow * 1024 + h * 64 + (lane >> 4) * 8;
    qf[0] = *(const bf16x8*)(qp);
    qf[1] = *(const bf16x8*)(qp + 32);
  }
#pragma unroll
  for (int it = 0; it < 8; ++it) {
    const int j = it * 32 + (tid >> 3);
    const int c = tid & 7;
    const uint4 kv = *(const uint4*)(K + kv0 + (size_t)j * 1024 + c * 8);
    *(uint4*)((char*)k_lds + j * 128 + ((c ^ (j & 7)) * 16)) = kv;
  }
  {
    const int j = (tid >> 1) * 2;
    const int half = tid & 1;
#pragma unroll
    for (int cc2 = 0; cc2 < 4; ++cc2) {
      const int chunk = half * 4 + cc2;
      const int d0 = chunk * 8;
      u16x8 a = *(const u16x8*)(V + kv0 + (size_t)j * 1024 + d0);
      u16x8 b = *(const u16x8*)(V + kv0 + (size_t)(j + 1) * 1024 + d0);
#pragma unroll
      for (int dd = 0; dd < 8; ++dd) {
        const int d = d0 + dd;
        unsigned int p = (unsigned int)a[dd] | ((unsigned int)b[dd] << 16);
        *(unsigned int*)((char*)v_t + d * 512 + (((j >> 3) ^ (d & 7)) * 16) + ((j & 7) * 2)) = p;
      }
    }
  }
  __syncthreads();

  f32x4 accs[16] = {};
#pragma unroll
  for (int jt = 0; jt < 16; ++jt) {
#pragma unroll
    for (int ks = 0; ks < 2; ++ks) {
      const int r = jt * 16 + (lane & 15);
      bf16x8 kf = *(const bf16x8*)((const char*)k_lds + r * 128 +
                                   (((ks * 4 + (lane >> 4)) ^ (r & 7)) * 16));
      accs[jt] = __builtin_amdgcn_mfma_f32_16x16x32_bf16(qf[ks], kf, accs[jt], 0, 0, 0);
    }
  }
  __syncthreads();

  float inv_[4];
#pragma unroll
  for (int r = 0; r < 4; ++r) {
    float m = accs[0][r];
#pragma unroll
    for (int jt = 1; jt < 16; ++jt) m = fmaxf(m, accs[jt][r]);
#pragma unroll
    for (int mk = 1; mk < 16; mk <<= 1) m = fmaxf(m, __shfl_xor(m, mk));
    float s = 0.f;
#pragma unroll
    for (int jt = 0; jt < 16; ++jt) {
      float p = __expf((accs[jt][r] - m) * 0.125f);
      accs[jt][r] = p;
      s += p;
    }
#pragma unroll
    for (int mk = 1; mk < 16; mk <<= 1) s += __shfl_xor(s, mk);
    inv_[r] = 1.0f / s;
  }
  char* pbase = (char*)k_lds + wid * 8192;
  {
    const int jc = lane & 15;
    const int i0 = (lane >> 4) * 4;
#pragma unroll
    for (int jt = 0; jt < 16; ++jt) {
      const int j = jt * 16 + jc;
#pragma unroll
      for (int r = 0; r < 4; ++r) {
        const int i = i0 + r;
        *(unsigned short*)(pbase + i * 512 + (((j >> 3) ^ (i & 7)) * 16) + ((j & 7) * 2)) =
            f2bf(accs[jt][r] * inv_[r]);
      }
    }
  }
  __syncthreads();

  f32x4 acco[4] = {};
#pragma unroll
  for (int jb = 0; jb < 8; ++jb) {
    const int i = lane & 15;
    bf16x8 pf = *(const bf16x8*)(pbase + i * 512 + (((jb * 4 + (lane >> 4)) ^ (i & 7)) * 16));
#pragma unroll
    for (int ni = 0; ni < 4; ++ni) {
      const int d = ni * 16 + (lane & 15);
      bf16x8 vf = *(const bf16x8*)((const char*)v_t + d * 512 +
                                   (((jb * 4 + (lane >> 4)) ^ (d & 7)) * 16));
      acco[ni] = __builtin_amdgcn_mfma_f32_16x16x32_bf16(pf, vf, acco[ni], 0, 0, 0);
    }
  }
  {
    const size_t row0 = (size_t)bc * 64 + wid * 16 + (lane >> 4) * 4;
#pragma unroll
    for (int ni = 0; ni < 4; ++ni) {
      const int col = h * 64 + ni * 16 + (lane & 15);
#pragma unroll
      for (int r = 0; r < 4; ++r) {
        O[(row0 + r) * 1024 + col] = f2bf(acco[ni][r]);
      }
    }
  }
}

extern "C" void kernel_launch(void* const* d_in, const int* in_sizes, int n_in,
                              void* d_out, int out_size, void* d_ws, size_t ws_size,
                              hipStream_t stream) {
  const float* h = (const float*)d_in[0];
  const float* e = (const float*)d_in[1];
  const float* Wq = (const float*)d_in[2];
  const float* bq = (const float*)d_in[3];
  const float* Wk = (const float*)d_in[4];
  const float* bk = (const float*)d_in[5];
  const float* Wv = (const float*)d_in[6];
  const float* bv = (const float*)d_in[7];
  const float* gamma = (const float*)d_in[8];
  const float* beta = (const float*)d_in[9];
  const float* Wo = (const float*)d_in[10];
  const float* bo = (const float*)d_in[11];
  float* out = (float*)d_out;

  char* ws = (char*)d_ws;
  unsigned short* x = (unsigned short*)ws;                        // 32MB (reused as o)
  unsigned short* q = (unsigned short*)(ws + (32ull << 20));      // 32MB
  unsigned short* kbuf = (unsigned short*)(ws + (64ull << 20));   // 128MB
  unsigned short* vbuf = (unsigned short*)(ws + (192ull << 20));  // 128MB
  unsigned short* ebf = (unsigned short*)(ws + (320ull << 20));   // 128MB
  unsigned short* wqT = (unsigned short*)(ws + (448ull << 20));   // 2MB
  unsigned short* wkvT = (unsigned short*)(ws + (450ull << 20));  // 4MB
  unsigned short* woT = (unsigned short*)(ws + (454ull << 20));   // 2MB
  unsigned short* o = x;

  dim3 tb(256);
  cvt_bf16<<<2048, tb, 0, stream>>>(e, ebf, 8388608L);
  transpose_all<<<dim3(16, 16, 4), tb, 0, stream>>>(Wq, Wk, Wv, Wo, wqT, wkvT, woT);
  ln_kernel<<<16384, tb, 0, stream>>>(h, gamma, beta, x);
  // Q = x @ Wq + bq
  gemm256<0><<<dim3(4, 64), dim3(512), 0, stream>>>(x, wqT, bq, nullptr, q, nullptr,
                                                    nullptr, nullptr);
  // [K|V] = e @ [Wk|Wv] + [bk|bv]
  gemm256<0><<<dim3(8, 256), dim3(512), 0, stream>>>(ebf, wkvT, bk, bv, kbuf, vbuf,
                                                     nullptr, nullptr);
  // attention
  attn_kernel<<<4096, tb, 0, stream>>>(q, kbuf, vbuf, o);
  // rows t<63: out = h
  fill_head<<<504, tb, 0, stream>>>(h, out);
  // rows t>=63: out = h + shift63(o @ Wo + bo)
  gemm256<1><<<dim3(4, 64), dim3(512), 0, stream>>>(o, woT, bo, nullptr, nullptr, nullptr,
                                                    h, out);
}